// Round 7
// baseline (95.887 us; speedup 1.0000x reference)
//
#include <hip/hip_runtime.h>

#define Bn 8
#define Nn 2048
#define Dn 128
#define OUTn 128

typedef __attribute__((ext_vector_type(8))) short bf16x8;     // MFMA A/B operand (8 bf16)
typedef __attribute__((ext_vector_type(8))) unsigned short ushort8;
typedef __attribute__((ext_vector_type(4))) float f32x4;      // MFMA C/D
typedef __attribute__((ext_vector_type(4))) int int4v;
typedef __attribute__((ext_vector_type(4))) float float4v;

__device__ __forceinline__ unsigned short f2bf(float f) {
  unsigned int u = __builtin_bit_cast(unsigned int, f);
  u += 0x7FFFu + ((u >> 16) & 1u);   // round-to-nearest-even
  return (unsigned short)(u >> 16);
}

// ---------------- prep: transpose input + transpose W ----------------
__global__ __launch_bounds__(256) void gcn_prep(const float* __restrict__ in,
                                                const float* __restrict__ W,
                                                unsigned short* __restrict__ inT,
                                                unsigned short* __restrict__ WT) {
  const int tid = threadIdx.x;
  if (blockIdx.x >= 256) {
    int gid = (blockIdx.x - 256) * 256 + tid;    // 0..32767
    int j = gid >> 8, k = gid & 255;             // WT[j][k] = W[k][j]
    WT[gid] = f2bf(W[k * OUTn + j]);
    return;
  }
  const int b = blockIdx.x >> 5;
  const int n0 = (blockIdx.x & 31) * 64;
  __shared__ __attribute__((aligned(16))) unsigned short lds[64][130];
  #pragma unroll
  for (int c = 0; c < 32; ++c) {
    int e = tid + c * 256;
    int i = e >> 7, d = e & 127;
    lds[i][d] = f2bf(in[((size_t)(b * Nn + n0 + i)) * Dn + d]);
  }
  __syncthreads();
  #pragma unroll
  for (int c = 0; c < 4; ++c) {
    int ch = tid + c * 256;
    int d = ch >> 3, g = (ch & 7) * 8;
    ushort8 v;
    #pragma unroll
    for (int e = 0; e < 8; ++e) v[e] = lds[g + e][d];
    *(ushort8*)(inT + ((size_t)(b * Dn + d)) * Nn + n0 + g) = v;
  }
}

// ---------------- main: barrier-free K-loop, explicit A+B register dbuf ----------
// 1024 blocks x 256 threads (4 waves). Block = 16 rows of one batch.
// Wave wv owns K-chunk [wv*512, +512): 16 steps of K=32, 8 MFMA each.
// A-frags direct from adj, B-frags direct from L2-hot inT; BOTH ping-pong
// register double-buffered (static indices, full unroll) so one full
// iteration of loads (10/lane) stays in flight -> vmcnt waits never drain
// the pipe. No LDS/barriers in the loop.
union EpiSMem {
  float buf[4][16][136];                     // 34816 B: per-kc partial C
  struct {
    unsigned short aggl[16][136];            // bf16 agg for GEMM2 A-frags
    float rowsum[16][4];
  } e;
};

__global__ __launch_bounds__(256, 2) void gcn_main(
    const float* __restrict__ input_, const int* __restrict__ adj,
    const float* __restrict__ bvec, const unsigned short* __restrict__ inT,
    const unsigned short* __restrict__ WT, float* __restrict__ out) {
  __shared__ EpiSMem sm;
  __shared__ float degp[4][16];

  const int tid = threadIdx.x;
  const int wv = tid >> 6;                   // = K-chunk index 0..3
  const int l = tid & 63, lr = l & 15, lg = l >> 4;

  // bijective XCD swizzle: 1024 blocks (%8==0) -> XCD x gets one batch
  const int swz = (blockIdx.x & 7) * 128 + (blockIdx.x >> 3);
  const int bb = swz >> 7;
  const int row0 = (swz & 127) * 16;
  const int grow0 = bb * Nn + row0;

  const int* arow = adj + (size_t)(grow0 + lr) * Nn + wv * 512 + lg * 8;
  const unsigned short* binT = inT + ((size_t)bb * Dn + lr) * Nn + wv * 512 + lg * 8;

  f32x4 acc[8] = {};
  int dsum = 0;

  // ping-pong register buffers (all statically indexed)
  int4v a0[2], a1[2];
  ushort8 b0[8], b1[8];

  // prologue: it=0 -> buf0, it=1 -> buf1 (issue order: oldest first)
  a0[0] = *(const int4v*)(arow);
  a0[1] = *(const int4v*)(arow + 4);
  #pragma unroll
  for (int cf = 0; cf < 8; ++cf)
    b0[cf] = *(const ushort8*)(binT + (size_t)cf * 16 * Nn);
  a1[0] = *(const int4v*)(arow + 32);
  a1[1] = *(const int4v*)(arow + 36);
  #pragma unroll
  for (int cf = 0; cf < 8; ++cf)
    b1[cf] = *(const ushort8*)(binT + (size_t)cf * 16 * Nn + 32);

  #pragma unroll
  for (int itp = 0; itp < 8; ++itp) {
    // ---- even iteration: consume buf0 (it = 2*itp), refill with it+2 ----
    {
      const int it = 2 * itp;
      ushort8 av;
      #pragma unroll
      for (int e = 0; e < 4; ++e) {
        int v0 = a0[0][e], v1 = a0[1][e];
        dsum += (v0 != 0) + (v1 != 0);
        av[e]     = (v0 != 0) ? (unsigned short)0x3F80u : (unsigned short)0u;
        av[e + 4] = (v1 != 0) ? (unsigned short)0x3F80u : (unsigned short)0u;
      }
      bf16x8 af = __builtin_bit_cast(bf16x8, av);
      #pragma unroll
      for (int cf = 0; cf < 8; ++cf)
        acc[cf] = __builtin_amdgcn_mfma_f32_16x16x32_bf16(
            af, __builtin_bit_cast(bf16x8, b0[cf]), acc[cf], 0, 0, 0);
      if (it + 2 < 16) {
        a0[0] = *(const int4v*)(arow + (it + 2) * 32);
        a0[1] = *(const int4v*)(arow + (it + 2) * 32 + 4);
        #pragma unroll
        for (int cf = 0; cf < 8; ++cf)
          b0[cf] = *(const ushort8*)(binT + (size_t)cf * 16 * Nn + (it + 2) * 32);
      }
    }
    // ---- odd iteration: consume buf1 (it = 2*itp+1), refill with it+2 ----
    {
      const int it = 2 * itp + 1;
      ushort8 av;
      #pragma unroll
      for (int e = 0; e < 4; ++e) {
        int v0 = a1[0][e], v1 = a1[1][e];
        dsum += (v0 != 0) + (v1 != 0);
        av[e]     = (v0 != 0) ? (unsigned short)0x3F80u : (unsigned short)0u;
        av[e + 4] = (v1 != 0) ? (unsigned short)0x3F80u : (unsigned short)0u;
      }
      bf16x8 af = __builtin_bit_cast(bf16x8, av);
      #pragma unroll
      for (int cf = 0; cf < 8; ++cf)
        acc[cf] = __builtin_amdgcn_mfma_f32_16x16x32_bf16(
            af, __builtin_bit_cast(bf16x8, b1[cf]), acc[cf], 0, 0, 0);
      if (it + 2 < 16) {
        a1[0] = *(const int4v*)(arow + (it + 2) * 32);
        a1[1] = *(const int4v*)(arow + (it + 2) * 32 + 4);
        #pragma unroll
        for (int cf = 0; cf < 8; ++cf)
          b1[cf] = *(const ushort8*)(binT + (size_t)cf * 16 * Nn + (it + 2) * 32);
      }
    }
  }

  // ---- per-kc partials to LDS; degree partial per row ----
  #pragma unroll
  for (int cf = 0; cf < 8; ++cf)
    #pragma unroll
    for (int reg = 0; reg < 4; ++reg)
      sm.buf[wv][lg * 4 + reg][cf * 16 + lr] = acc[cf][reg];
  {
    int s = dsum;
    s += __shfl_xor(s, 16);
    s += __shfl_xor(s, 32);                  // lanes {lr,+16,+32,+48} summed
    if (l < 16) degp[wv][lr] = (float)s;
  }
  __syncthreads();

  // ---- sum 4 kc-partials, /deg, pack bf16 ----
  const int row = tid >> 4, c0 = (tid & 15) * 8;
  float dg = degp[0][row] + degp[1][row] + degp[2][row] + degp[3][row];
  if (dg == 0.f) dg = 1.f;
  const float inv = 1.f / dg;
  ushort8 packed;
  #pragma unroll
  for (int e = 0; e < 8; ++e) {
    float ssum = sm.buf[0][row][c0 + e] + sm.buf[1][row][c0 + e] +
                 sm.buf[2][row][c0 + e] + sm.buf[3][row][c0 + e];
    packed[e] = f2bf(ssum * inv);
  }
  __syncthreads();                           // buf reads done before aliased write
  *(ushort8*)&sm.e.aggl[row][c0] = packed;
  __syncthreads();

  // ---- GEMM2: [x | agg] @ W (K=256); x direct from input_, B from WT ----
  f32x4 acc2[2] = {};
  const float* xrow = input_ + (size_t)(grow0 + lr) * Dn;
  #pragma unroll
  for (int ks = 0; ks < 8; ++ks) {
    bf16x8 af;
    if (ks < 4) {
      float4v f0 = *(const float4v*)(xrow + ks * 32 + lg * 8);
      float4v f1 = *(const float4v*)(xrow + ks * 32 + lg * 8 + 4);
      ushort8 vv;
      #pragma unroll
      for (int e = 0; e < 4; ++e) { vv[e] = f2bf(f0[e]); vv[e + 4] = f2bf(f1[e]); }
      af = __builtin_bit_cast(bf16x8, vv);
    } else {
      af = *(const bf16x8*)&sm.e.aggl[lr][(ks - 4) * 32 + lg * 8];
    }
    #pragma unroll
    for (int cf = 0; cf < 2; ++cf) {
      bf16x8 bw = *(const bf16x8*)(WT + (size_t)(wv * 32 + cf * 16 + lr) * 256 +
                                   ks * 32 + lg * 8);
      acc2[cf] = __builtin_amdgcn_mfma_f32_16x16x32_bf16(af, bw, acc2[cf], 0, 0, 0);
    }
  }

  // ---- bias + sigmoid + row L2-norm + store ----
  float bcol[2];
  bcol[0] = bvec[wv * 32 + lr];
  bcol[1] = bvec[wv * 32 + 16 + lr];
  float sg[2][4];
  #pragma unroll
  for (int cf = 0; cf < 2; ++cf)
    #pragma unroll
    for (int reg = 0; reg < 4; ++reg) {
      float x = acc2[cf][reg] + bcol[cf];
      sg[cf][reg] = 1.0f / (1.0f + expf(-x));
    }
  #pragma unroll
  for (int reg = 0; reg < 4; ++reg) {
    float p = sg[0][reg] * sg[0][reg] + sg[1][reg] * sg[1][reg];
    p += __shfl_xor(p, 1);
    p += __shfl_xor(p, 2);
    p += __shfl_xor(p, 4);
    p += __shfl_xor(p, 8);
    if (lr == 0) sm.e.rowsum[lg * 4 + reg][wv] = p;
  }
  __syncthreads();
  #pragma unroll
  for (int reg = 0; reg < 4; ++reg) {
    const int r2 = lg * 4 + reg;
    float nrm = rsqrtf(sm.e.rowsum[r2][0] + sm.e.rowsum[r2][1] +
                       sm.e.rowsum[r2][2] + sm.e.rowsum[r2][3]);
    #pragma unroll
    for (int cf = 0; cf < 2; ++cf)
      out[(size_t)(grow0 + r2) * OUTn + wv * 32 + cf * 16 + lr] =
          sg[cf][reg] * nrm;
  }
}

extern "C" void kernel_launch(void* const* d_in, const int* in_sizes, int n_in,
                              void* d_out, int out_size, void* d_ws, size_t ws_size,
                              hipStream_t stream) {
  (void)in_sizes; (void)n_in; (void)out_size; (void)ws_size;
  const float* input_ = (const float*)d_in[0];
  const int* adj = (const int*)d_in[1];
  const float* W = (const float*)d_in[2];
  const float* bvec = (const float*)d_in[3];
  float* out = (float*)d_out;

  unsigned short* inT = (unsigned short*)d_ws;                 // 4 MB
  unsigned short* WT = inT + (size_t)Bn * Dn * Nn;             // 64 KB

  hipLaunchKernelGGL(gcn_prep, dim3(384), dim3(256), 0, stream, input_, W, inT, WT);
  hipLaunchKernelGGL(gcn_main, dim3(1024), dim3(256), 0, stream,
                     input_, adj, bvec, inT, WT, out);
}

// Round 8
// 47.548 us; speedup vs baseline: 2.0167x; 2.0167x over previous
//
#include <hip/hip_runtime.h>

#define Bn 8
#define Nn 2048
#define Dn 128
#define OUTn 128

typedef __attribute__((ext_vector_type(8))) short bf16x8;     // MFMA A/B operand (8 bf16)
typedef __attribute__((ext_vector_type(8))) unsigned short ushort8;
typedef __attribute__((ext_vector_type(4))) float f32x4;      // MFMA C/D
typedef __attribute__((ext_vector_type(4))) int int4v;
typedef __attribute__((ext_vector_type(4))) unsigned int uint4v;
typedef __attribute__((ext_vector_type(4))) float float4v;

__device__ __forceinline__ unsigned short f2bf(float f) {
  unsigned int u = __builtin_bit_cast(unsigned int, f);
  u += 0x7FFFu + ((u >> 16) & 1u);   // round-to-nearest-even
  return (unsigned short)(u >> 16);
}

// ---------------- prep: transpose input + transpose W ----------------
__global__ __launch_bounds__(256) void gcn_prep(const float* __restrict__ in,
                                                const float* __restrict__ W,
                                                unsigned short* __restrict__ inT,
                                                unsigned short* __restrict__ WT) {
  const int tid = threadIdx.x;
  if (blockIdx.x >= 256) {
    int gid = (blockIdx.x - 256) * 256 + tid;    // 0..32767
    int j = gid >> 8, k = gid & 255;             // WT[j][k] = W[k][j]
    WT[gid] = f2bf(W[k * OUTn + j]);
    return;
  }
  const int b = blockIdx.x >> 5;
  const int n0 = (blockIdx.x & 31) * 64;
  __shared__ __attribute__((aligned(16))) unsigned short lds[64][130];
  #pragma unroll
  for (int c = 0; c < 32; ++c) {
    int e = tid + c * 256;
    int i = e >> 7, d = e & 127;
    lds[i][d] = f2bf(in[((size_t)(b * Nn + n0 + i)) * Dn + d]);
  }
  __syncthreads();
  #pragma unroll
  for (int c = 0; c < 4; ++c) {
    int ch = tid + c * 256;
    int d = ch >> 3, g = (ch & 7) * 8;
    ushort8 v;
    #pragma unroll
    for (int e = 0; e < 8; ++e) v[e] = lds[g + e][d];
    *(ushort8*)(inT + ((size_t)(b * Dn + d)) * Nn + n0 + g) = v;
  }
}

// ---------------- main: 2-phase global_load_lds DMA pipeline ----------------
// 512 blocks x 256 threads (4 waves). Block = 32 rows of one batch, BK=64.
// A tile (adj, raw int32 32x64) and B tile (inT bf16 128x64) staged by DMA
// into double-buffered LDS; 16B-chunk XOR swizzle (chunk ^= row&7) applied on
// the GLOBAL source and on the ds_read side (linear DMA dest - rule #21).
// A converted int->bf16 at frag-read (adj in {0,1}: bf16 = v * 0x3F80).
// One __syncthreads per K-tile (its vmcnt drain IS the pipeline wait; the
// next tile's DMA was issued before compute, so latency hides under MFMA).
union SMem {
  struct {
    int A[2][32][64];                  // 16 KB (swizzled content, linear layout)
    unsigned short Bs[2][128][64];     // 32 KB (swizzled content, linear layout)
  } s;                                 // 48 KB
  struct {
    unsigned short aggl[32][136];      // bf16 agg for GEMM2 A-frags
    float rowsum[32][2];
    float degs[32];
  } e;
};

#define STAGE(cur, kt)                                                         \
  {                                                                            \
    _Pragma("unroll")                                                          \
    for (int c = 0; c < 2; ++c) {                                              \
      const int r_ = c * 16 + wv * 4 + (l >> 4);                               \
      const int cg_ = (l & 15) ^ (r_ & 7);                                     \
      const int* gsrc_ = adjB + (size_t)r_ * Nn + (kt) * 64 + cg_ * 4;         \
      __builtin_amdgcn_global_load_lds(                                        \
          (const __attribute__((address_space(1))) void*)gsrc_,                \
          (__attribute__((address_space(3))) void*)((char*)&sm.s.A[cur][0][0] +\
                                                    c * 4096 + wv * 1024),     \
          16, 0, 0);                                                           \
    }                                                                          \
    _Pragma("unroll")                                                          \
    for (int c = 0; c < 4; ++c) {                                              \
      const int d_ = c * 32 + wv * 8 + (l >> 3);                               \
      const int cg_ = (l & 7) ^ (d_ & 7);                                      \
      const unsigned short* gsrc_ = inTb + (size_t)d_ * Nn + (kt) * 64 + cg_ * 8; \
      __builtin_amdgcn_global_load_lds(                                        \
          (const __attribute__((address_space(1))) void*)gsrc_,                \
          (__attribute__((address_space(3))) void*)((char*)&sm.s.Bs[cur][0][0] +\
                                                    c * 4096 + wv * 1024),     \
          16, 0, 0);                                                           \
    }                                                                          \
  }

#define COMPUTE(cur)                                                           \
  {                                                                            \
    _Pragma("unroll")                                                          \
    for (int kc = 0; kc < 2; ++kc) {                                           \
      const int c0_ = kc * 8 + lg * 2;                                         \
      int4v ai0 = *(const int4v*)(Abase + ((c0_ ^ swz8) * 16));                \
      int4v ai1 = *(const int4v*)(Abase + (((c0_ + 1) ^ swz8) * 16));          \
      dsum += ai0[0] + ai0[1] + ai0[2] + ai0[3] +                              \
              ai1[0] + ai1[1] + ai1[2] + ai1[3];                               \
      uint4v aw;                                                               \
      aw[0] = (unsigned)ai0[0] * 0x3F80u + (unsigned)ai0[1] * 0x3F800000u;     \
      aw[1] = (unsigned)ai0[2] * 0x3F80u + (unsigned)ai0[3] * 0x3F800000u;     \
      aw[2] = (unsigned)ai1[0] * 0x3F80u + (unsigned)ai1[1] * 0x3F800000u;     \
      aw[3] = (unsigned)ai1[2] * 0x3F80u + (unsigned)ai1[3] * 0x3F800000u;     \
      bf16x8 af = __builtin_bit_cast(bf16x8, aw);                              \
      _Pragma("unroll")                                                        \
      for (int cf = 0; cf < 4; ++cf) {                                         \
        bf16x8 bfm = *(const bf16x8*)(Bbase + (size_t)cf * 16 * 128 +          \
                                      (((kc * 4 + lg) ^ swz8) * 16));          \
        acc[cf] = __builtin_amdgcn_mfma_f32_16x16x32_bf16(af, bfm, acc[cf],    \
                                                          0, 0, 0);            \
      }                                                                        \
    }                                                                          \
  }

__global__ __launch_bounds__(256, 2) void gcn_main(
    const float* __restrict__ input_, const int* __restrict__ adj,
    const float* __restrict__ bvec, const unsigned short* __restrict__ inT,
    const unsigned short* __restrict__ WT, float* __restrict__ out) {
  __shared__ SMem sm;
  const int tid = threadIdx.x;
  const int wv = tid >> 6;
  const int l = tid & 63, lr = l & 15, lg = (l >> 4) & 3;
  const int rg = wv >> 1, ch = wv & 1;

  // bijective XCD swizzle: 512 blocks (%8==0) -> XCD x gets batch x
  const int swz = (blockIdx.x & 7) * 64 + (blockIdx.x >> 3);
  const int bb = swz >> 6;
  const int row0 = (swz & 63) * 32;
  const int grow0 = bb * Nn + row0;

  const int* adjB = adj + (size_t)grow0 * Nn;
  const unsigned short* inTb = inT + (size_t)bb * Dn * Nn;

  const int swz8 = lr & 7;                       // frag-read swizzle (row&7)
  const char* Bbase0;
  f32x4 acc[4] = {};
  int dsum = 0;

  // prologue: stage tile 0
  STAGE(0, 0);
  __syncthreads();

  #pragma unroll 1
  for (int ktp = 0; ktp < 16; ++ktp) {
    const int kt0 = 2 * ktp;
    {
      STAGE(1, kt0 + 1);
      const char* Abase = (const char*)&sm.s.A[0][0][0] + (rg * 16 + lr) * 256;
      const char* Bbase = (const char*)&sm.s.Bs[0][0][0] + (ch * 64 + lr) * 128;
      COMPUTE(0);
      __syncthreads();
    }
    {
      if (kt0 + 2 < 32) STAGE(0, kt0 + 2);
      const char* Abase = (const char*)&sm.s.A[1][0][0] + (rg * 16 + lr) * 256;
      const char* Bbase = (const char*)&sm.s.Bs[1][0][0] + (ch * 64 + lr) * 128;
      COMPUTE(1);
      __syncthreads();
    }
  }
  (void)Bbase0;

  // ---- degree (adj in {0,1}: dsum is the partial row sum) ----
  {
    int s = dsum;
    s += __shfl_xor(s, 16);
    s += __shfl_xor(s, 32);                      // lanes lr,+16,+32,+48 summed
    if (l < 16) sm.e.degs[rg * 16 + l] = (s == 0) ? 1.0f : (float)s;
  }
  __syncthreads();

  // ---- agg = acc/deg staged as bf16 for GEMM2 ----
  float dgi[4];
  #pragma unroll
  for (int reg = 0; reg < 4; ++reg)
    dgi[reg] = 1.0f / sm.e.degs[rg * 16 + lg * 4 + reg];
  #pragma unroll
  for (int cf = 0; cf < 4; ++cf)
    #pragma unroll
    for (int reg = 0; reg < 4; ++reg)
      sm.e.aggl[rg * 16 + lg * 4 + reg][ch * 64 + cf * 16 + lr] =
          f2bf(acc[cf][reg] * dgi[reg]);
  __syncthreads();

  // ---- GEMM2: [x | agg] @ W (K=256); x direct from input_, B from WT ----
  f32x4 acc2[4] = {};
  const float* xrow = input_ + (size_t)(grow0 + rg * 16 + lr) * Dn;
  #pragma unroll
  for (int ks = 0; ks < 8; ++ks) {
    bf16x8 af;
    if (ks < 4) {
      float4v f0 = *(const float4v*)(xrow + ks * 32 + lg * 8);
      float4v f1 = *(const float4v*)(xrow + ks * 32 + lg * 8 + 4);
      ushort8 vv;
      #pragma unroll
      for (int e = 0; e < 4; ++e) { vv[e] = f2bf(f0[e]); vv[e + 4] = f2bf(f1[e]); }
      af = __builtin_bit_cast(bf16x8, vv);
    } else {
      af = *(const bf16x8*)&sm.e.aggl[rg * 16 + lr][(ks - 4) * 32 + lg * 8];
    }
    #pragma unroll
    for (int cf = 0; cf < 4; ++cf) {
      bf16x8 bw = *(const bf16x8*)(WT + (size_t)(ch * 64 + cf * 16 + lr) * 256 +
                                   ks * 32 + lg * 8);
      acc2[cf] = __builtin_amdgcn_mfma_f32_16x16x32_bf16(af, bw, acc2[cf], 0, 0, 0);
    }
  }

  // ---- bias + sigmoid + row L2-norm + store ----
  float bcol[4];
  #pragma unroll
  for (int cf = 0; cf < 4; ++cf) bcol[cf] = bvec[ch * 64 + cf * 16 + lr];
  float sg[4][4];
  #pragma unroll
  for (int cf = 0; cf < 4; ++cf)
    #pragma unroll
    for (int reg = 0; reg < 4; ++reg) {
      float x = acc2[cf][reg] + bcol[cf];
      sg[cf][reg] = 1.0f / (1.0f + expf(-x));
    }
  #pragma unroll
  for (int reg = 0; reg < 4; ++reg) {
    float p = 0.f;
    #pragma unroll
    for (int cf = 0; cf < 4; ++cf) p += sg[cf][reg] * sg[cf][reg];
    p += __shfl_xor(p, 1);
    p += __shfl_xor(p, 2);
    p += __shfl_xor(p, 4);
    p += __shfl_xor(p, 8);
    if (lr == 0) sm.e.rowsum[rg * 16 + lg * 4 + reg][ch] = p;
  }
  __syncthreads();
  #pragma unroll
  for (int reg = 0; reg < 4; ++reg) {
    const int row = rg * 16 + lg * 4 + reg;
    float nrm = rsqrtf(sm.e.rowsum[row][0] + sm.e.rowsum[row][1]);
    #pragma unroll
    for (int cf = 0; cf < 4; ++cf)
      out[(size_t)(grow0 + row) * OUTn + ch * 64 + cf * 16 + lr] =
          sg[cf][reg] * nrm;
  }
}

extern "C" void kernel_launch(void* const* d_in, const int* in_sizes, int n_in,
                              void* d_out, int out_size, void* d_ws, size_t ws_size,
                              hipStream_t stream) {
  (void)in_sizes; (void)n_in; (void)out_size; (void)ws_size;
  const float* input_ = (const float*)d_in[0];
  const int* adj = (const int*)d_in[1];
  const float* W = (const float*)d_in[2];
  const float* bvec = (const float*)d_in[3];
  float* out = (float*)d_out;

  unsigned short* inT = (unsigned short*)d_ws;                 // 4 MB
  unsigned short* WT = inT + (size_t)Bn * Dn * Nn;             // 64 KB

  hipLaunchKernelGGL(gcn_prep, dim3(384), dim3(256), 0, stream, input_, W, inT, WT);
  hipLaunchKernelGGL(gcn_main, dim3(512), dim3(256), 0, stream,
                     input_, adj, bvec, inT, WT, out);
}

// Round 9
// 43.672 us; speedup vs baseline: 2.1956x; 1.0887x over previous
//
#include <hip/hip_runtime.h>

#define Bn 8
#define Nn 2048
#define Dn 128
#define OUTn 128

typedef __attribute__((ext_vector_type(8))) short bf16x8;     // MFMA A/B operand (8 bf16)
typedef __attribute__((ext_vector_type(8))) unsigned short ushort8;
typedef __attribute__((ext_vector_type(4))) float f32x4;      // MFMA C/D
typedef __attribute__((ext_vector_type(4))) int int4v;
typedef __attribute__((ext_vector_type(4))) unsigned int uint4v;
typedef __attribute__((ext_vector_type(4))) float float4v;

__device__ __forceinline__ unsigned short f2bf(float f) {
  unsigned int u = __builtin_bit_cast(unsigned int, f);
  u += 0x7FFFu + ((u >> 16) & 1u);   // round-to-nearest-even
  return (unsigned short)(u >> 16);
}

// ---------------- prep: transpose input + transpose W ----------------
__global__ __launch_bounds__(256) void gcn_prep(const float* __restrict__ in,
                                                const float* __restrict__ W,
                                                unsigned short* __restrict__ inT,
                                                unsigned short* __restrict__ WT) {
  const int tid = threadIdx.x;
  if (blockIdx.x >= 256) {
    int gid = (blockIdx.x - 256) * 256 + tid;    // 0..32767
    int j = gid >> 8, k = gid & 255;             // WT[j][k] = W[k][j]
    WT[gid] = f2bf(W[k * OUTn + j]);
    return;
  }
  const int b = blockIdx.x >> 5;
  const int n0 = (blockIdx.x & 31) * 64;
  __shared__ __attribute__((aligned(16))) unsigned short lds[64][130];
  #pragma unroll
  for (int c = 0; c < 32; ++c) {
    int e = tid + c * 256;
    int i = e >> 7, d = e & 127;
    lds[i][d] = f2bf(in[((size_t)(b * Nn + n0 + i)) * Dn + d]);
  }
  __syncthreads();
  #pragma unroll
  for (int c = 0; c < 4; ++c) {
    int ch = tid + c * 256;
    int d = ch >> 3, g = (ch & 7) * 8;
    ushort8 v;
    #pragma unroll
    for (int e = 0; e < 8; ++e) v[e] = lds[g + e][d];
    *(ushort8*)(inT + ((size_t)(b * Dn + d)) * Nn + n0 + g) = v;
  }
}

// ---------------- main: counted-vmcnt DMA pipeline, 3-buffer rotation --------
// 512 blocks x 256 threads (4 waves). Block = 32 rows of one batch, BK=64.
// Per iter: s_waitcnt vmcnt(6) [tile kt done, tile kt+1's 6 loads IN FLIGHT,
// never drained] -> raw s_barrier -> STAGE(kt+2) into 3rd buffer -> COMPUTE(kt).
// A raw int32 in LDS, converted at frag-read (adj in {0,1}: bf16 = v*0x3F80).
// 16B-chunk XOR swizzle (chunk ^= row&7) on global source + ds_read (rule #21).
// LDS 72KB -> 2 blocks/CU; 2 tiles in flight = 48KB/block outstanding.
union SMem {
  struct {
    int A[3][32][64];                  // 24 KB (swizzled content, linear layout)
    unsigned short Bs[3][128][64];     // 48 KB
  } s;                                 // 72 KB
  struct {
    unsigned short aggl[32][136];      // bf16 agg for GEMM2 A-frags
    float rowsum[32][2];
    float degs[32];
  } e;
};

#define STAGE(cur, kt) do {                                                    \
    _Pragma("unroll")                                                          \
    for (int c_ = 0; c_ < 2; ++c_) {                                           \
      const int r_ = c_ * 16 + wv * 4 + (l >> 4);                              \
      const int cg_ = (l & 15) ^ (r_ & 7);                                     \
      const int* gsrc_ = adjB + (size_t)r_ * Nn + (kt) * 64 + cg_ * 4;         \
      __builtin_amdgcn_global_load_lds(                                        \
          (const __attribute__((address_space(1))) void*)gsrc_,                \
          (__attribute__((address_space(3))) void*)(smc + (cur) * 8192 +       \
                                                   c_ * 4096 + wv * 1024),     \
          16, 0, 0);                                                           \
    }                                                                          \
    _Pragma("unroll")                                                          \
    for (int c_ = 0; c_ < 4; ++c_) {                                           \
      const int d_ = c_ * 32 + wv * 8 + (l >> 3);                              \
      const int cg_ = (l & 7) ^ (d_ & 7);                                      \
      const unsigned short* gsrc_ = inTb + (size_t)d_ * Nn + (kt) * 64 + cg_ * 8; \
      __builtin_amdgcn_global_load_lds(                                        \
          (const __attribute__((address_space(1))) void*)gsrc_,                \
          (__attribute__((address_space(3))) void*)(smc + 24576 +              \
                                                   (cur) * 16384 +             \
                                                   c_ * 4096 + wv * 1024),     \
          16, 0, 0);                                                           \
    }                                                                          \
  } while (0)

#define COMPUTE(cur) do {                                                      \
    const char* Abase = smc + (cur) * 8192 + (rg * 16 + lr) * 256;             \
    const char* Bbase = smc + 24576 + (cur) * 16384 + (ch * 64 + lr) * 128;    \
    _Pragma("unroll")                                                          \
    for (int kc = 0; kc < 2; ++kc) {                                           \
      const int c0_ = kc * 8 + lg * 2;                                         \
      int4v ai0 = *(const int4v*)(Abase + ((c0_ ^ swz8) * 16));                \
      int4v ai1 = *(const int4v*)(Abase + (((c0_ + 1) ^ swz8) * 16));          \
      dsum += ai0[0] + ai0[1] + ai0[2] + ai0[3] +                              \
              ai1[0] + ai1[1] + ai1[2] + ai1[3];                               \
      uint4v aw;                                                               \
      aw[0] = (unsigned)ai0[0] * 0x3F80u + (unsigned)ai0[1] * 0x3F800000u;     \
      aw[1] = (unsigned)ai0[2] * 0x3F80u + (unsigned)ai0[3] * 0x3F800000u;     \
      aw[2] = (unsigned)ai1[0] * 0x3F80u + (unsigned)ai1[1] * 0x3F800000u;     \
      aw[3] = (unsigned)ai1[2] * 0x3F80u + (unsigned)ai1[3] * 0x3F800000u;     \
      bf16x8 af = __builtin_bit_cast(bf16x8, aw);                              \
      _Pragma("unroll")                                                        \
      for (int cf = 0; cf < 4; ++cf) {                                         \
        bf16x8 bfm = *(const bf16x8*)(Bbase + (size_t)cf * 16 * 128 +          \
                                      (((kc * 4 + lg) ^ swz8) * 16));          \
        acc[cf] = __builtin_amdgcn_mfma_f32_16x16x32_bf16(af, bfm, acc[cf],    \
                                                          0, 0, 0);            \
      }                                                                        \
    }                                                                          \
  } while (0)

#define WAITBAR(N) do {                                                        \
    asm volatile("s_waitcnt vmcnt(" #N ")" ::: "memory");                      \
    __builtin_amdgcn_s_barrier();                                              \
    __builtin_amdgcn_sched_barrier(0);                                         \
  } while (0)

__global__ __launch_bounds__(256, 2) void gcn_main(
    const float* __restrict__ input_, const int* __restrict__ adj,
    const float* __restrict__ bvec, const unsigned short* __restrict__ inT,
    const unsigned short* __restrict__ WT, float* __restrict__ out) {
  __shared__ SMem sm;
  char* smc = (char*)&sm;
  const int tid = threadIdx.x;
  const int wv = tid >> 6;
  const int l = tid & 63, lr = l & 15, lg = (l >> 4) & 3;
  const int rg = wv >> 1, ch = wv & 1;

  // bijective XCD swizzle: 512 blocks (%8==0) -> XCD x gets batch x
  const int swz = (blockIdx.x & 7) * 64 + (blockIdx.x >> 3);
  const int bb = swz >> 6;
  const int row0 = (swz & 63) * 32;
  const int grow0 = bb * Nn + row0;

  const int* adjB = adj + (size_t)grow0 * Nn;
  const unsigned short* inTb = inT + (size_t)bb * Dn * Nn;

  const int swz8 = lr & 7;                       // frag-read swizzle (row&7)
  f32x4 acc[4] = {};
  int dsum = 0;

  // prologue: tiles 0,1 staged (12 loads in flight)
  STAGE(0, 0);
  STAGE(1, 1);

  #pragma unroll 1
  for (int j = 0; j < 10; ++j) {
    const int kt = 3 * j;
    WAITBAR(6); STAGE(2, kt + 2); COMPUTE(0);
    WAITBAR(6); STAGE(0, kt + 3); COMPUTE(1);
    WAITBAR(6); STAGE(1, kt + 4); COMPUTE(2);
  }
  // peel kt=30 (buf0), kt=31 (buf1); no further stages
  WAITBAR(6); COMPUTE(0);
  WAITBAR(0); COMPUTE(1);

  __syncthreads();                               // close K-loop: sm re-used below

  // ---- degree (adj in {0,1}: dsum is the partial row sum) ----
  {
    int s = dsum;
    s += __shfl_xor(s, 16);
    s += __shfl_xor(s, 32);                      // lanes lr,+16,+32,+48 summed
    if (l < 16) sm.e.degs[rg * 16 + l] = (s == 0) ? 1.0f : (float)s;
  }
  __syncthreads();

  // ---- agg = acc/deg staged as bf16 for GEMM2 ----
  float dgi[4];
  #pragma unroll
  for (int reg = 0; reg < 4; ++reg)
    dgi[reg] = 1.0f / sm.e.degs[rg * 16 + lg * 4 + reg];
  #pragma unroll
  for (int cf = 0; cf < 4; ++cf)
    #pragma unroll
    for (int reg = 0; reg < 4; ++reg)
      sm.e.aggl[rg * 16 + lg * 4 + reg][ch * 64 + cf * 16 + lr] =
          f2bf(acc[cf][reg] * dgi[reg]);
  __syncthreads();

  // ---- GEMM2: [x | agg] @ W (K=256); x direct from input_, B from WT ----
  f32x4 acc2[4] = {};
  const float* xrow = input_ + (size_t)(grow0 + rg * 16 + lr) * Dn;
  #pragma unroll
  for (int ks = 0; ks < 8; ++ks) {
    bf16x8 af;
    if (ks < 4) {
      float4v f0 = *(const float4v*)(xrow + ks * 32 + lg * 8);
      float4v f1 = *(const float4v*)(xrow + ks * 32 + lg * 8 + 4);
      ushort8 vv;
      #pragma unroll
      for (int e = 0; e < 4; ++e) { vv[e] = f2bf(f0[e]); vv[e + 4] = f2bf(f1[e]); }
      af = __builtin_bit_cast(bf16x8, vv);
    } else {
      af = *(const bf16x8*)&sm.e.aggl[rg * 16 + lr][(ks - 4) * 32 + lg * 8];
    }
    #pragma unroll
    for (int cf = 0; cf < 4; ++cf) {
      bf16x8 bw = *(const bf16x8*)(WT + (size_t)(ch * 64 + cf * 16 + lr) * 256 +
                                   ks * 32 + lg * 8);
      acc2[cf] = __builtin_amdgcn_mfma_f32_16x16x32_bf16(af, bw, acc2[cf], 0, 0, 0);
    }
  }

  // ---- bias + sigmoid + row L2-norm + store ----
  float bcol[4];
  #pragma unroll
  for (int cf = 0; cf < 4; ++cf) bcol[cf] = bvec[ch * 64 + cf * 16 + lr];
  float sg[4][4];
  #pragma unroll
  for (int cf = 0; cf < 4; ++cf)
    #pragma unroll
    for (int reg = 0; reg < 4; ++reg) {
      float x = acc2[cf][reg] + bcol[cf];
      sg[cf][reg] = 1.0f / (1.0f + expf(-x));
    }
  #pragma unroll
  for (int reg = 0; reg < 4; ++reg) {
    float p = 0.f;
    #pragma unroll
    for (int cf = 0; cf < 4; ++cf) p += sg[cf][reg] * sg[cf][reg];
    p += __shfl_xor(p, 1);
    p += __shfl_xor(p, 2);
    p += __shfl_xor(p, 4);
    p += __shfl_xor(p, 8);
    if (lr == 0) sm.e.rowsum[rg * 16 + lg * 4 + reg][ch] = p;
  }
  __syncthreads();
  #pragma unroll
  for (int reg = 0; reg < 4; ++reg) {
    const int row = rg * 16 + lg * 4 + reg;
    float nrm = rsqrtf(sm.e.rowsum[row][0] + sm.e.rowsum[row][1]);
    #pragma unroll
    for (int cf = 0; cf < 4; ++cf)
      out[(size_t)(grow0 + row) * OUTn + ch * 64 + cf * 16 + lr] =
          sg[cf][reg] * nrm;
  }
}

extern "C" void kernel_launch(void* const* d_in, const int* in_sizes, int n_in,
                              void* d_out, int out_size, void* d_ws, size_t ws_size,
                              hipStream_t stream) {
  (void)in_sizes; (void)n_in; (void)out_size; (void)ws_size;
  const float* input_ = (const float*)d_in[0];
  const int* adj = (const int*)d_in[1];
  const float* W = (const float*)d_in[2];
  const float* bvec = (const float*)d_in[3];
  float* out = (float*)d_out;

  unsigned short* inT = (unsigned short*)d_ws;                 // 4 MB
  unsigned short* WT = inT + (size_t)Bn * Dn * Nn;             // 64 KB

  hipLaunchKernelGGL(gcn_prep, dim3(384), dim3(256), 0, stream, input_, W, inT, WT);
  hipLaunchKernelGGL(gcn_main, dim3(512), dim3(256), 0, stream,
                     input_, adj, bvec, inT, WT, out);
}